// Round 3
// baseline (1139.792 us; speedup 1.0000x reference)
//
#include <hip/hip_runtime.h>
#include <math.h>

#define N_NODES 1000000
#define DIM 128
#define TOPK 16
#define BLOCKS1 1024
#define THREADS 256
#define NCAND (BLOCKS1 * TOPK)

typedef float f32x4 __attribute__((ext_vector_type(4)));

__device__ __forceinline__ bool lexless(float v1, int i1, float v2, int i2) {
    return (v1 < v2) || (v1 == v2 && i1 < i2);
}

// Insert (v,i) into ascending top-16 list held entirely in registers.
// Fully unrolled: all indices compile-time constant (no scratch spill).
__device__ __forceinline__ void insert16(float (&bv)[TOPK], int (&bi)[TOPK],
                                         float v, int i) {
    if (!lexless(v, i, bv[TOPK - 1], bi[TOPK - 1])) return;
#pragma unroll
    for (int j = TOPK - 1; j > 0; --j) {
        if (lexless(v, i, bv[j - 1], bi[j - 1])) {
            bv[j] = bv[j - 1]; bi[j] = bi[j - 1];
        } else {
            bv[j] = v; bi[j] = i;
            return;
        }
    }
    bv[0] = v; bi[0] = i;
}

__device__ __forceinline__ float rowdist2(f32x4 x, f32x4 s) {
    float d = x.x - s.x; float a = d * d;
    d = x.y - s.y; a = fmaf(d, d, a);
    d = x.z - s.z; a = fmaf(d, d, a);
    d = x.w - s.w; a = fmaf(d, d, a);
    return a;
}

// Stage 1: distances + per-block top-16.
// Wave w covers rows {2w, 2w+1} (contiguous 1KB per load inst: each 32-lane
// half-wave reads one 512B row as float4/lane). 4 rows in flight per
// half-wave (+0,+8,+16,+24; loop stride 32) for memory-level parallelism.
// Plain cached loads (NOT nontemporal): streaming reads through L2 match the
// 6.3 TB/s microbench; nt was the prime suspect for the BW shortfall.
__global__ __launch_bounds__(THREADS, 4) void som_dist_stage1(
    const float* __restrict__ samples,
    const float* __restrict__ nodes,
    float* __restrict__ cand_val,
    int* __restrict__ cand_idx) {
    const int tid  = threadIdx.x;
    const int lane = tid & 63;
    const int w    = tid >> 6;        // wave 0..3
    const int half = lane >> 5;       // 0/1 within wave
    const int l2   = lane & 31;       // lane within half

    const f32x4 s = ((const f32x4*)samples)[l2];

    // chunk per block, rounded to 32 so steady-state iters have no guards
    const int npb   = (((N_NODES + BLOCKS1 - 1) / BLOCKS1) + 31) & ~31;
    const int start = blockIdx.x * npb;
    const int end   = min(start + npb, N_NODES);

    float bv[TOPK];
    int   bi[TOPK];
#pragma unroll
    for (int j = 0; j < TOPK; ++j) { bv[j] = INFINITY; bi[j] = 0x7fffffff; }

    const bool owner = (l2 == 0);

    for (int base = start + w * 2 + half; base < end; base += 32) {
        const int nA = base, nB = base + 8, nC = base + 16, nD = base + 24;
        const bool vB = (nB < end), vC = (nC < end), vD = (nD < end);

        const f32x4 xA = *((const f32x4*)(nodes + (size_t)nA * DIM) + l2);
        f32x4 xB = {0.f, 0.f, 0.f, 0.f}, xC = xB, xD = xB;
        if (vB) xB = *((const f32x4*)(nodes + (size_t)nB * DIM) + l2);
        if (vC) xC = *((const f32x4*)(nodes + (size_t)nC * DIM) + l2);
        if (vD) xD = *((const f32x4*)(nodes + (size_t)nD * DIM) + l2);

        float aA = rowdist2(xA, s);
        float aB = rowdist2(xB, s);
        float aC = rowdist2(xC, s);
        float aD = rowdist2(xD, s);

#pragma unroll
        for (int m = 1; m <= 16; m <<= 1) {
            aA += __shfl_xor(aA, m, 64);
            aB += __shfl_xor(aB, m, 64);
            aC += __shfl_xor(aC, m, 64);
            aD += __shfl_xor(aD, m, 64);
        }
        if (owner) {
            insert16(bv, bi, aA, nA);
            if (vB) insert16(bv, bi, aB, nB);
            if (vC) insert16(bv, bi, aC, nC);
            if (vD) insert16(bv, bi, aD, nD);
        }
    }

    // Block merge: 8 owner lists (lanes 0/32 of 4 waves) -> LDS -> thread 0.
    __shared__ float lv[8 * TOPK];
    __shared__ int   li[8 * TOPK];
    const int oid = tid >> 5;  // 0..7
    if (owner) {
#pragma unroll
        for (int j = 0; j < TOPK; ++j) {
            lv[oid * TOPK + j] = bv[j];
            li[oid * TOPK + j] = bi[j];
        }
    }
    __syncthreads();
    if (tid == 0) {
        float rv[TOPK];
        int   ri[TOPK];
#pragma unroll
        for (int j = 0; j < TOPK; ++j) { rv[j] = INFINITY; ri[j] = 0x7fffffff; }
        for (int c = 0; c < 8 * TOPK; ++c) insert16(rv, ri, lv[c], li[c]);
#pragma unroll
        for (int j = 0; j < TOPK; ++j) {
            cand_val[blockIdx.x * TOPK + j] = rv[j];
            cand_idx[blockIdx.x * TOPK + j] = ri[j];
        }
    }
}

// Stage 2: ONE wave (64 lanes). Each lane inserts 256 candidates (vectorized
// float4/int4 loads, coalesced), then 16 barrier-free shuffle-argmin rounds.
__global__ __launch_bounds__(64) void som_topk_final(
    const float* __restrict__ cand_val,
    const int* __restrict__ cand_idx,
    float* __restrict__ out) {
    const int lane = threadIdx.x;  // 0..63

    float bv[TOPK];
    int   bi[TOPK];
#pragma unroll
    for (int j = 0; j < TOPK; ++j) { bv[j] = INFINITY; bi[j] = 0x7fffffff; }

    for (int c = lane * 4; c < NCAND; c += 64 * 4) {
        const f32x4 v = *(const f32x4*)(cand_val + c);
        const int4  i = *(const int4*)(cand_idx + c);
        insert16(bv, bi, v.x, i.x);
        insert16(bv, bi, v.y, i.y);
        insert16(bv, bi, v.z, i.z);
        insert16(bv, bi, v.w, i.w);
    }

#pragma unroll
    for (int r = 0; r < TOPK; ++r) {
        float v = bv[0];
        int   i = bi[0];
        int   t = lane;
#pragma unroll
        for (int m = 1; m <= 32; m <<= 1) {
            const float ov = __shfl_xor(v, m, 64);
            const int   oi = __shfl_xor(i, m, 64);
            const int   ot = __shfl_xor(t, m, 64);
            if (lexless(ov, oi, v, i)) { v = ov; i = oi; t = ot; }
        }
        if (lane == 0) {
            out[r]        = (float)i;     // index
            out[TOPK + r] = sqrtf(v);     // distance
        }
        if (lane == t) {  // winner pops its front element
#pragma unroll
            for (int j = 0; j < TOPK - 1; ++j) { bv[j] = bv[j + 1]; bi[j] = bi[j + 1]; }
            bv[TOPK - 1] = INFINITY; bi[TOPK - 1] = 0x7fffffff;
        }
    }
}

extern "C" void kernel_launch(void* const* d_in, const int* in_sizes, int n_in,
                              void* d_out, int out_size, void* d_ws, size_t ws_size,
                              hipStream_t stream) {
    const float* samples = (const float*)d_in[0];
    const float* nodes   = (const float*)d_in[1];
    float* out = (float*)d_out;

    float* cand_val = (float*)d_ws;
    int*   cand_idx = (int*)((char*)d_ws + NCAND * sizeof(float));

    som_dist_stage1<<<BLOCKS1, THREADS, 0, stream>>>(samples, nodes, cand_val, cand_idx);
    som_topk_final<<<1, 64, 0, stream>>>(cand_val, cand_idx, out);
}

// Round 4
// 1065.140 us; speedup vs baseline: 1.0701x; 1.0701x over previous
//
#include <hip/hip_runtime.h>
#include <math.h>

#define N_NODES 1000000
#define DIM 128
#define TOPK 16
#define BLOCKS1 1024
#define THREADS 256
#define NCAND (BLOCKS1 * TOPK)
#define THREADS2 1024
#define CPT (NCAND / THREADS2)   // 16 candidates per stage-2 thread

typedef float f32x4 __attribute__((ext_vector_type(4)));
typedef unsigned long long u64;
typedef unsigned int u32;

// Pack (dist2, idx) so that u64 '<' == lexicographic (dist2, idx) '<'.
// dist2 >= 0 so IEEE f32 bits are monotone in value.
__device__ __forceinline__ u64 packcand(float d2, int idx) {
    return ((u64)__float_as_uint(d2) << 32) | (u32)idx;
}

// Ascending top-16 of packed u64, registers only, early-out guard.
__device__ __forceinline__ void insert16(u64 (&b)[TOPK], u64 v) {
    if (v >= b[TOPK - 1]) return;
#pragma unroll
    for (int j = TOPK - 1; j > 0; --j) {
        if (v < b[j - 1]) {
            b[j] = b[j - 1];
        } else {
            b[j] = v;
            return;
        }
    }
    b[0] = v;
}

__device__ __forceinline__ float rowdist2(f32x4 x, f32x4 s) {
    float d = x.x - s.x; float a = d * d;
    d = x.y - s.y; a = fmaf(d, d, a);
    d = x.z - s.z; a = fmaf(d, d, a);
    d = x.w - s.w; a = fmaf(d, d, a);
    return a;
}

// Stage 1: distances + per-block top-16 (packed u64 candidates).
// Each 32-lane half-wave owns one 512B row (float4/lane); full wave = 1KB
// contiguous per load inst. 4 rows in flight per half-wave for MLP.
__global__ __launch_bounds__(THREADS, 4) void som_dist_stage1(
    const float* __restrict__ samples,
    const float* __restrict__ nodes,
    u64* __restrict__ cand) {
    const int tid  = threadIdx.x;
    const int lane = tid & 63;
    const int w    = tid >> 6;        // wave 0..3
    const int half = lane >> 5;       // 0/1 within wave
    const int l2   = lane & 31;       // lane within half

    const f32x4 s = ((const f32x4*)samples)[l2];

    const int npb   = (((N_NODES + BLOCKS1 - 1) / BLOCKS1) + 31) & ~31;
    const int start = blockIdx.x * npb;
    const int end   = min(start + npb, N_NODES);

    u64 b[TOPK];
#pragma unroll
    for (int j = 0; j < TOPK; ++j) b[j] = ~0ull;

    const bool owner = (l2 == 0);

    for (int base = start + w * 2 + half; base < end; base += 32) {
        const int nA = base, nB = base + 8, nC = base + 16, nD = base + 24;
        const bool vB = (nB < end), vC = (nC < end), vD = (nD < end);

        const f32x4 xA = *((const f32x4*)(nodes + (size_t)nA * DIM) + l2);
        f32x4 xB = {0.f, 0.f, 0.f, 0.f}, xC = xB, xD = xB;
        if (vB) xB = *((const f32x4*)(nodes + (size_t)nB * DIM) + l2);
        if (vC) xC = *((const f32x4*)(nodes + (size_t)nC * DIM) + l2);
        if (vD) xD = *((const f32x4*)(nodes + (size_t)nD * DIM) + l2);

        float aA = rowdist2(xA, s);
        float aB = rowdist2(xB, s);
        float aC = rowdist2(xC, s);
        float aD = rowdist2(xD, s);

#pragma unroll
        for (int m = 1; m <= 16; m <<= 1) {
            aA += __shfl_xor(aA, m, 64);
            aB += __shfl_xor(aB, m, 64);
            aC += __shfl_xor(aC, m, 64);
            aD += __shfl_xor(aD, m, 64);
        }
        if (owner) {
            insert16(b, packcand(aA, nA));
            if (vB) insert16(b, packcand(aB, nB));
            if (vC) insert16(b, packcand(aC, nC));
            if (vD) insert16(b, packcand(aD, nD));
        }
    }

    // Block merge: 8 owner lists -> LDS -> thread 0 -> global candidates.
    __shared__ u64 lb[8 * TOPK];
    const int oid = tid >> 5;  // 0..7
    if (owner) {
#pragma unroll
        for (int j = 0; j < TOPK; ++j) lb[oid * TOPK + j] = b[j];
    }
    __syncthreads();
    if (tid == 0) {
        u64 rb[TOPK];
#pragma unroll
        for (int j = 0; j < TOPK; ++j) rb[j] = ~0ull;
        for (int c = 0; c < 8 * TOPK; ++c) insert16(rb, lb[c]);
#pragma unroll
        for (int j = 0; j < TOPK; ++j) cand[blockIdx.x * TOPK + j] = rb[j];
    }
}

// Stage 2: 1 block x 1024 threads. Each thread holds 16 packed candidates in
// registers; 16 rounds of fully BRANCHLESS extraction:
//   thread-min(16 selects) -> wave shuffle-min -> LDS min over 16 waves ->
//   winner removed via 16 branchless compares. No insertion sorts.
__global__ __launch_bounds__(THREADS2) void som_topk_final(
    const u64* __restrict__ cand,
    float* __restrict__ out) {
    const int tid = threadIdx.x;

    u64 c[CPT];
#pragma unroll
    for (int k = 0; k < CPT; ++k) c[k] = cand[tid + k * THREADS2];

    __shared__ u64 wmin[THREADS2 / 64];
    __shared__ u64 s_win;

    for (int r = 0; r < TOPK; ++r) {
        // branchless thread-local min
        u64 m = c[0];
#pragma unroll
        for (int k = 1; k < CPT; ++k) m = (c[k] < m) ? c[k] : m;
        // wave shuffle-min (branchless selects)
#pragma unroll
        for (int s = 1; s <= 32; s <<= 1) {
            const u64 o = __shfl_xor(m, s, 64);
            m = (o < m) ? o : m;
        }
        if ((tid & 63) == 0) wmin[tid >> 6] = m;
        __syncthreads();
        if (tid == 0) {
            u64 g = wmin[0];
#pragma unroll
            for (int q = 1; q < THREADS2 / 64; ++q)
                g = (wmin[q] < g) ? wmin[q] : g;
            s_win = g;
            out[r]        = (float)(u32)(g & 0xffffffffu);        // index
            out[TOPK + r] = sqrtf(__uint_as_float((u32)(g >> 32))); // distance
        }
        __syncthreads();
        const u64 win = s_win;
        // branchless removal (u64s are unique: idx field distinct)
#pragma unroll
        for (int k = 0; k < CPT; ++k) c[k] = (c[k] == win) ? ~0ull : c[k];
    }
}

extern "C" void kernel_launch(void* const* d_in, const int* in_sizes, int n_in,
                              void* d_out, int out_size, void* d_ws, size_t ws_size,
                              hipStream_t stream) {
    const float* samples = (const float*)d_in[0];
    const float* nodes   = (const float*)d_in[1];
    float* out = (float*)d_out;
    u64* cand = (u64*)d_ws;

    som_dist_stage1<<<BLOCKS1, THREADS, 0, stream>>>(samples, nodes, cand);
    som_topk_final<<<1, THREADS2, 0, stream>>>(cand, out);
}

// Round 6
// 717.426 us; speedup vs baseline: 1.5887x; 1.4847x over previous
//
#include <hip/hip_runtime.h>
#include <math.h>

#define N_NODES 1000000
#define DIM 128
#define TOPK 16
#define BLOCKS1 1024
#define THREADS 256
#define NCAND (BLOCKS1 * TOPK)
#define THREADS2 1024
#define CPT (NCAND / THREADS2)   // 16 candidates per stage-2 thread

typedef float f32x4 __attribute__((ext_vector_type(4)));
typedef unsigned long long u64;
typedef unsigned int u32;

// Pack (dist2, idx) so that u64 '<' == lexicographic (dist2, idx) '<'.
// dist2 >= 0 so IEEE f32 bits are monotone in value.
__device__ __forceinline__ u64 packcand(float d2, int idx) {
    return ((u64)__float_as_uint(d2) << 32) | (u32)idx;
}

// BRANCHLESS ascending top-16 insert: compare-select sift chain, all array
// indices compile-time constant -> list stays in VGPRs (no scratch).
// The guard is pure exec-mask predication (no memory, no loop-carried branch).
__device__ __forceinline__ void insert16(u64 (&b)[TOPK], u64 v) {
    if (v < b[TOPK - 1]) {
#pragma unroll
        for (int j = 0; j < TOPK; ++j) {
            const bool lt = v < b[j];
            const u64 lo = lt ? v : b[j];
            const u64 hi = lt ? b[j] : v;
            b[j] = lo;
            v = hi;
        }
    }
}

__device__ __forceinline__ float rowdist2(f32x4 x, f32x4 s) {
    float d = x.x - s.x; float a = d * d;
    d = x.y - s.y; a = fmaf(d, d, a);
    d = x.z - s.z; a = fmaf(d, d, a);
    d = x.w - s.w; a = fmaf(d, d, a);
    return a;
}

// Stage 1: distances + per-block top-16 (packed u64 candidates).
// Each 32-lane half-wave owns one 512B row (float4/lane); full wave = 1KB
// contiguous per load inst. 4 rows in flight per half-wave for MLP.
__global__ __launch_bounds__(THREADS, 4) void som_dist_stage1(
    const float* __restrict__ samples,
    const float* __restrict__ nodes,
    u64* __restrict__ cand) {
    const int tid  = threadIdx.x;
    const int lane = tid & 63;
    const int w    = tid >> 6;        // wave 0..3
    const int half = lane >> 5;       // 0/1 within wave
    const int l2   = lane & 31;       // lane within half

    const f32x4 s = ((const f32x4*)samples)[l2];

    const int npb   = (((N_NODES + BLOCKS1 - 1) / BLOCKS1) + 31) & ~31;
    const int start = blockIdx.x * npb;
    const int end   = min(start + npb, N_NODES);

    u64 b[TOPK];
#pragma unroll
    for (int j = 0; j < TOPK; ++j) b[j] = ~0ull;

    const bool owner = (l2 == 0);

    for (int base = start + w * 2 + half; base < end; base += 32) {
        const int nA = base, nB = base + 8, nC = base + 16, nD = base + 24;
        const bool vB = (nB < end), vC = (nC < end), vD = (nD < end);

        const f32x4 xA = *((const f32x4*)(nodes + (size_t)nA * DIM) + l2);
        f32x4 xB = {0.f, 0.f, 0.f, 0.f}, xC = xB, xD = xB;
        if (vB) xB = *((const f32x4*)(nodes + (size_t)nB * DIM) + l2);
        if (vC) xC = *((const f32x4*)(nodes + (size_t)nC * DIM) + l2);
        if (vD) xD = *((const f32x4*)(nodes + (size_t)nD * DIM) + l2);

        float aA = rowdist2(xA, s);
        float aB = rowdist2(xB, s);
        float aC = rowdist2(xC, s);
        float aD = rowdist2(xD, s);

#pragma unroll
        for (int m = 1; m <= 16; m <<= 1) {
            aA += __shfl_xor(aA, m, 64);
            aB += __shfl_xor(aB, m, 64);
            aC += __shfl_xor(aC, m, 64);
            aD += __shfl_xor(aD, m, 64);
        }
        if (owner) {
            // invalid slots become ~0ull sentinels -> guard rejects them
            const u64 pA = packcand(aA, nA);
            const u64 pB = vB ? packcand(aB, nB) : ~0ull;
            const u64 pC = vC ? packcand(aC, nC) : ~0ull;
            const u64 pD = vD ? packcand(aD, nD) : ~0ull;
            insert16(b, pA);
            insert16(b, pB);
            insert16(b, pC);
            insert16(b, pD);
        }
    }

    // Block merge: 8 owner lists -> LDS -> thread 0 -> global candidates.
    __shared__ u64 lb[8 * TOPK];
    const int oid = tid >> 5;  // 0..7
    if (owner) {
#pragma unroll
        for (int j = 0; j < TOPK; ++j) lb[oid * TOPK + j] = b[j];
    }
    __syncthreads();
    if (tid == 0) {
        u64 rb[TOPK];
#pragma unroll
        for (int j = 0; j < TOPK; ++j) rb[j] = ~0ull;
        for (int c = 0; c < 8 * TOPK; ++c) insert16(rb, lb[c]);
#pragma unroll
        for (int j = 0; j < TOPK; ++j) cand[blockIdx.x * TOPK + j] = rb[j];
    }
}

// Stage 2: 1 block x 1024 threads. Each thread holds 16 packed candidates in
// registers; 16 rounds of fully BRANCHLESS extraction:
//   thread-min(16 selects) -> wave shuffle-min -> LDS min over 16 waves ->
//   winner removed via branchless compares.
__global__ __launch_bounds__(THREADS2) void som_topk_final(
    const u64* __restrict__ cand,
    float* __restrict__ out) {
    const int tid = threadIdx.x;

    u64 c[CPT];
#pragma unroll
    for (int k = 0; k < CPT; ++k) c[k] = cand[tid + k * THREADS2];

    __shared__ u64 wmin[THREADS2 / 64];
    __shared__ u64 s_win;

    for (int r = 0; r < TOPK; ++r) {
        // branchless thread-local min
        u64 m = c[0];
#pragma unroll
        for (int k = 1; k < CPT; ++k) m = (c[k] < m) ? c[k] : m;
        // wave shuffle-min (branchless selects)
#pragma unroll
        for (int s = 1; s <= 32; s <<= 1) {
            const u64 o = __shfl_xor(m, s, 64);
            m = (o < m) ? o : m;
        }
        if ((tid & 63) == 0) wmin[tid >> 6] = m;
        __syncthreads();
        if (tid == 0) {
            u64 g = wmin[0];
#pragma unroll
            for (int q = 1; q < THREADS2 / 64; ++q)
                g = (wmin[q] < g) ? wmin[q] : g;
            s_win = g;
            out[r]        = (float)(u32)(g & 0xffffffffu);          // index
            out[TOPK + r] = sqrtf(__uint_as_float((u32)(g >> 32))); // distance
        }
        __syncthreads();
        const u64 win = s_win;
        // branchless removal (packed values unique: idx field distinct)
#pragma unroll
        for (int k = 0; k < CPT; ++k) c[k] = (c[k] == win) ? ~0ull : c[k];
    }
}

extern "C" void kernel_launch(void* const* d_in, const int* in_sizes, int n_in,
                              void* d_out, int out_size, void* d_ws, size_t ws_size,
                              hipStream_t stream) {
    const float* samples = (const float*)d_in[0];
    const float* nodes   = (const float*)d_in[1];
    float* out = (float*)d_out;
    u64* cand = (u64*)d_ws;

    som_dist_stage1<<<BLOCKS1, THREADS, 0, stream>>>(samples, nodes, cand);
    som_topk_final<<<1, THREADS2, 0, stream>>>(cand, out);
}